// Round 8
// baseline (470.386 us; speedup 1.0000x reference)
//
#include <hip/hip_runtime.h>
#include <math.h>

// LSEP loss: loss = log1p( sum_rows (sum_{t==0} exp(x)) * (sum_{t>0} exp(-x)) ) / B
// R3..R7: diagnostic round (resubmitted across infra failures; probes have
// never yet executed). Real kernel = R0 shape (row per thread, grid-stride)
// with sign-XOR + fma element op. Plus two pure-bandwidth probe kernels to
// discriminate: environment BW cap vs two-stream cap vs compute-chain cap.

constexpr int  ROWS  = 2000000;
constexpr int  BLOCK = 256;
constexpr int  GRID  = 2048;               // 8 blocks/CU
constexpr long N4    = (long)ROWS * 6;     // 12M float4 (and 12M int4)

// ---------------- real kernel ----------------
__global__ __launch_bounds__(BLOCK) void lsep_main(
        const float4* __restrict__ input,
        const int4*   __restrict__ target,
        double*       __restrict__ partials)
{
    const int tid    = blockIdx.x * BLOCK + threadIdx.x;
    const int stride = GRID * BLOCK;
    double acc = 0.0;

    for (int row = tid; row < ROWS; row += stride) {
        const long b4 = (long)row * 6;
        const float4 x0 = input[b4+0], x1 = input[b4+1], x2 = input[b4+2],
                     x3 = input[b4+3], x4 = input[b4+4], x5 = input[b4+5];
        const int4   t0 = target[b4+0], t1 = target[b4+1], t2 = target[b4+2],
                     t3 = target[b4+3], t4 = target[b4+4], t5 = target[b4+5];

        float asum = 0.0f, bsum = 0.0f;
        #define LSEP_ELEM(xc, tc) { \
            const float xs = __int_as_float(__float_as_int(xc) ^ ((tc) << 31)); \
            const float e  = __expf(xs); \
            const float tf = (float)(tc); \
            bsum = fmaf(e, tf, bsum); \
            asum = fmaf(e, 1.0f - tf, asum); }
        LSEP_ELEM(x0.x, t0.x) LSEP_ELEM(x0.y, t0.y) LSEP_ELEM(x0.z, t0.z) LSEP_ELEM(x0.w, t0.w)
        LSEP_ELEM(x1.x, t1.x) LSEP_ELEM(x1.y, t1.y) LSEP_ELEM(x1.z, t1.z) LSEP_ELEM(x1.w, t1.w)
        LSEP_ELEM(x2.x, t2.x) LSEP_ELEM(x2.y, t2.y) LSEP_ELEM(x2.z, t2.z) LSEP_ELEM(x2.w, t2.w)
        LSEP_ELEM(x3.x, t3.x) LSEP_ELEM(x3.y, t3.y) LSEP_ELEM(x3.z, t3.z) LSEP_ELEM(x3.w, t3.w)
        LSEP_ELEM(x4.x, t4.x) LSEP_ELEM(x4.y, t4.y) LSEP_ELEM(x4.z, t4.z) LSEP_ELEM(x4.w, t4.w)
        LSEP_ELEM(x5.x, t5.x) LSEP_ELEM(x5.y, t5.y) LSEP_ELEM(x5.z, t5.z) LSEP_ELEM(x5.w, t5.w)
        #undef LSEP_ELEM

        acc += (double)asum * (double)bsum;
    }

    __shared__ double sred[BLOCK / 64];
    #pragma unroll
    for (int off = 32; off > 0; off >>= 1)
        acc += __shfl_down(acc, off, 64);
    const int t = threadIdx.x;
    if ((t & 63) == 0) sred[t >> 6] = acc;
    __syncthreads();
    if (t == 0)
        partials[blockIdx.x] = (sred[0] + sred[1]) + (sred[2] + sred[3]);
}

// ---------------- probe: both streams, add-only ----------------
__global__ __launch_bounds__(BLOCK) void probe_two(
        const float4* __restrict__ input,
        const int4*   __restrict__ target,
        float*        __restrict__ out)
{
    const int tid    = blockIdx.x * BLOCK + threadIdx.x;
    const int stride = GRID * BLOCK;
    float acc = 0.0f; int iacc = 0;
    for (long i = tid; i < N4; i += stride) {
        const float4 x = input[i];
        const int4   t = target[i];
        acc  += (x.x + x.y) + (x.z + x.w);
        iacc += (t.x + t.y) + (t.z + t.w);
    }
    acc += (float)iacc;
    #pragma unroll
    for (int off = 32; off > 0; off >>= 1)
        acc += __shfl_down(acc, off, 64);
    __shared__ float sred[BLOCK / 64];
    const int t = threadIdx.x;
    if ((t & 63) == 0) sred[t >> 6] = acc;
    __syncthreads();
    if (t == 0) out[blockIdx.x] = (sred[0] + sred[1]) + (sred[2] + sred[3]);
}

// ---------------- probe: input stream only ----------------
__global__ __launch_bounds__(BLOCK) void probe_one(
        const float4* __restrict__ input,
        float*        __restrict__ out)
{
    const int tid    = blockIdx.x * BLOCK + threadIdx.x;
    const int stride = GRID * BLOCK;
    float acc = 0.0f;
    for (long i = tid; i < N4; i += stride) {
        const float4 x = input[i];
        acc += (x.x + x.y) + (x.z + x.w);
    }
    #pragma unroll
    for (int off = 32; off > 0; off >>= 1)
        acc += __shfl_down(acc, off, 64);
    __shared__ float sred[BLOCK / 64];
    const int t = threadIdx.x;
    if ((t & 63) == 0) sred[t >> 6] = acc;
    __syncthreads();
    if (t == 0) out[blockIdx.x] = (sred[0] + sred[1]) + (sred[2] + sred[3]);
}

// ---------------- finalize ----------------
__global__ void lsep_finalize(const double* __restrict__ partials,
                              float* __restrict__ out)
{
    __shared__ double sred[4];
    const int t = threadIdx.x;
    double s = 0.0;
    for (int i = t; i < GRID; i += 256) s += partials[i];
    #pragma unroll
    for (int off = 32; off > 0; off >>= 1)
        s += __shfl_down(s, off, 64);
    if ((t & 63) == 0) sred[t >> 6] = s;
    __syncthreads();
    if (t == 0)
        out[0] = (float)(log1p((sred[0] + sred[1]) + (sred[2] + sred[3])) / (double)ROWS);
}

extern "C" void kernel_launch(void* const* d_in, const int* in_sizes, int n_in,
                              void* d_out, int out_size, void* d_ws, size_t ws_size,
                              hipStream_t stream) {
    const float4* input  = (const float4*)d_in[0];
    const int4*   target = (const int4*)d_in[1];
    double* partials = (double*)d_ws;                          // 2048 f64 = 16 KB
    float*  probes   = (float*)((char*)d_ws + GRID * sizeof(double)); // 2x 8 KB
    float*  out      = (float*)d_out;

    lsep_main<<<GRID, BLOCK, 0, stream>>>(input, target, partials);
    probe_two<<<GRID, BLOCK, 0, stream>>>(input, target, probes);
    probe_one<<<GRID, BLOCK, 0, stream>>>(input, probes + GRID);
    lsep_finalize<<<1, 256, 0, stream>>>(partials, out);
}

// Round 10
// 375.674 us; speedup vs baseline: 1.2521x; 1.2521x over previous
//
#include <hip/hip_runtime.h>
#include <math.h>

// LSEP loss: loss = log1p( sum_rows (sum_{t==0} exp(x)) * (sum_{t>0} exp(-x)) ) / B
// R9/R10: probe-shaped main kernel (resubmitted after acquisition timeout).
// R8's probes showed the same arrays stream at ~6 TB/s with flat unguarded
// loads (probe_two ~65us) while all row-structured variants sat at 3 TB/s.
// This kernel copies probe_two's load structure exactly: flat contiguous
// float4/int4, no guards (exact tiling, 12M/768 = 15625 tiles), then pairs
// rows via a small double-buffered LDS stage.
//   tile = 768 float4s = 128 rows; thread k loads 3 f4 + 3 i4, computes 12
//   exps, writes 3 (a,b) float2 partials to LDS; 1 barrier; threads 0..127
//   sum 6 consecutive pairs (3x ds_read_b128) and accumulate a*b in f64.

constexpr int  ROWS   = 2000000;
constexpr int  BLOCK  = 256;
constexpr int  GRID   = 2048;              // 8 blocks/CU
constexpr int  K      = 3;                 // float4s per thread per tile
constexpr int  TILE4  = BLOCK * K;         // 768 float4s per tile
constexpr int  TROWS  = TILE4 / 6;         // 128 rows per tile
constexpr int  NTILES = 15625;             // 12,000,000 / 768 exactly - no tail

__global__ __launch_bounds__(BLOCK) void lsep_main(
        const float4* __restrict__ input,
        const int4*   __restrict__ target,
        double*       __restrict__ partials)
{
    __shared__ float2 pair[2][TILE4];      // double buffer, 12 KB
    __shared__ double sred[BLOCK / 64];

    const int t = threadIdx.x;
    double acc = 0.0;

    int buf = 0;
    for (int tile = blockIdx.x; tile < NTILES; tile += GRID, buf ^= 1) {
        const long base = (long)tile * TILE4;

        // ---- flat unguarded loads (probe_two pattern) ----
        const float4 x0 = input[base + t];
        const float4 x1 = input[base + t + BLOCK];
        const float4 x2 = input[base + t + 2 * BLOCK];
        const int4   g0 = target[base + t];
        const int4   g1 = target[base + t + BLOCK];
        const int4   g2 = target[base + t + 2 * BLOCK];

        // ---- per-float4 partial pair (a = sum exp(x)|t==0, b = sum exp(-x)|t==1) ----
        float2 p0, p1, p2;
        #define LSEP_P4(dst, xv, tv) { \
            float a_ = 0.0f, b_ = 0.0f; \
            { const float e = __expf(__int_as_float(__float_as_int(xv.x) ^ (tv.x << 31))); \
              const float f = (float)tv.x; b_ = fmaf(e, f, b_); a_ = fmaf(e, 1.0f - f, a_); } \
            { const float e = __expf(__int_as_float(__float_as_int(xv.y) ^ (tv.y << 31))); \
              const float f = (float)tv.y; b_ = fmaf(e, f, b_); a_ = fmaf(e, 1.0f - f, a_); } \
            { const float e = __expf(__int_as_float(__float_as_int(xv.z) ^ (tv.z << 31))); \
              const float f = (float)tv.z; b_ = fmaf(e, f, b_); a_ = fmaf(e, 1.0f - f, a_); } \
            { const float e = __expf(__int_as_float(__float_as_int(xv.w) ^ (tv.w << 31))); \
              const float f = (float)tv.w; b_ = fmaf(e, f, b_); a_ = fmaf(e, 1.0f - f, a_); } \
            dst = make_float2(a_, b_); }
        LSEP_P4(p0, x0, g0)
        LSEP_P4(p1, x1, g1)
        LSEP_P4(p2, x2, g2)
        #undef LSEP_P4

        // ---- contiguous LDS writes ----
        pair[buf][t]             = p0;
        pair[buf][t + BLOCK]     = p1;
        pair[buf][t + 2 * BLOCK] = p2;
        __syncthreads();
        // (double buffer: next tile writes the other half, so no trailing
        //  barrier needed; a wave can't rewrite this buffer (tile i+2) without
        //  all waves passing barrier i+1, which follows their reads below.)

        // ---- row combine: row t uses pairs 6t..6t+5 = float4s 3t..3t+2 ----
        if (t < TROWS) {
            const float4* pr = reinterpret_cast<const float4*>(pair[buf]) + 3 * t;
            const float4 q0 = pr[0], q1 = pr[1], q2 = pr[2];
            const float a = (q0.x + q0.z) + (q1.x + q1.z) + (q2.x + q2.z);
            const float b = (q0.y + q0.w) + (q1.y + q1.w) + (q2.y + q2.w);
            acc += (double)a * (double)b;
        }
    }

    // ---- block reduction (f64) ----
    #pragma unroll
    for (int off = 32; off > 0; off >>= 1)
        acc += __shfl_down(acc, off, 64);
    if ((t & 63) == 0) sred[t >> 6] = acc;
    __syncthreads();
    if (t == 0)
        partials[blockIdx.x] = (sred[0] + sred[1]) + (sred[2] + sred[3]);
}

__global__ void lsep_finalize(const double* __restrict__ partials,
                              float* __restrict__ out)
{
    __shared__ double sred[4];
    const int t = threadIdx.x;
    double s = 0.0;
    for (int i = t; i < GRID; i += 256) s += partials[i];
    #pragma unroll
    for (int off = 32; off > 0; off >>= 1)
        s += __shfl_down(s, off, 64);
    if ((t & 63) == 0) sred[t >> 6] = s;
    __syncthreads();
    if (t == 0)
        out[0] = (float)(log1p((sred[0] + sred[1]) + (sred[2] + sred[3])) / (double)ROWS);
}

extern "C" void kernel_launch(void* const* d_in, const int* in_sizes, int n_in,
                              void* d_out, int out_size, void* d_ws, size_t ws_size,
                              hipStream_t stream) {
    const float4* input  = (const float4*)d_in[0];
    const int4*   target = (const int4*)d_in[1];
    double* partials = (double*)d_ws;      // 2048 f64 = 16 KB
    float*  out      = (float*)d_out;

    lsep_main<<<GRID, BLOCK, 0, stream>>>(input, target, partials);
    lsep_finalize<<<1, 256, 0, stream>>>(partials, out);
}